// Round 9
// baseline (309.894 us; speedup 1.0000x reference)
//
#include <hip/hip_runtime.h>

#define EPSV 0.001f

// ---------------------------------------------------------------------------
// Kernel A: MLP only. 2048 blocks x 256 threads; block = 8 rows of one MLP.
// All 2048 blocks co-resident (17.7 KB LDS -> 8 blocks/CU); W1 (2x256KB)
// stays L2-resident. Instruction-bound, ~20 us.
//   wd[bz*1024+n] = exp(mlp_d(x)[b,n,z]),  wu[...] = mlp_o(x)[b,n,z]
// ---------------------------------------------------------------------------
__global__ __launch_bounds__(256) void mlp_kernel(
    const float* __restrict__ x,
    const float* __restrict__ dW0, const float* __restrict__ db0,
    const float* __restrict__ dW1, const float* __restrict__ db1,
    const float* __restrict__ dW2, const float* __restrict__ db2,
    const float* __restrict__ oW0, const float* __restrict__ ob0,
    const float* __restrict__ oW1, const float* __restrict__ ob1,
    const float* __restrict__ oW2, const float* __restrict__ ob2,
    float* __restrict__ wd, float* __restrict__ wu)
{
    __shared__ float xs[8][32];
    __shared__ float h1[8][260];
    __shared__ float h2[8][260];

    const int t     = threadIdx.x;
    const int mlpid = blockIdx.x;         // 0..2047
    const int msel  = mlpid & 1;          // 0 = diag MLP, 1 = offdiag MLP
    const int row0  = (mlpid >> 1) << 3;  // 8 rows of flattened (8192, 32) x

    const float* W0 = msel ? oW0 : dW0;  const float* b0 = msel ? ob0 : db0;
    const float* W1 = msel ? oW1 : dW1;  const float* b1 = msel ? ob1 : db1;
    const float* W2 = msel ? oW2 : dW2;  const float* b2 = msel ? ob2 : db2;

    ((float*)xs)[t] = x[row0 * 32 + t];
    __syncthreads();

    // ----- layer 1: (8 x 32) @ (32 x 256); thread t owns hidden unit t -----
    {
        float acc1[8];
        const float bb = b0[t];
        #pragma unroll
        for (int r = 0; r < 8; ++r) acc1[r] = bb;
        #pragma unroll
        for (int k4 = 0; k4 < 8; ++k4) {
            const float w0 = W0[(k4 * 4 + 0) * 256 + t];
            const float w1 = W0[(k4 * 4 + 1) * 256 + t];
            const float w2 = W0[(k4 * 4 + 2) * 256 + t];
            const float w3 = W0[(k4 * 4 + 3) * 256 + t];
            #pragma unroll
            for (int r = 0; r < 8; ++r) {
                const float4 h = *reinterpret_cast<const float4*>(&xs[r][k4 * 4]);
                acc1[r] = fmaf(h.w, w3, fmaf(h.z, w2, fmaf(h.y, w1, fmaf(h.x, w0, acc1[r]))));
            }
        }
        #pragma unroll
        for (int r = 0; r < 8; ++r) h1[r][t] = fmaxf(acc1[r], 0.0f);
    }
    __syncthreads();

    // ----- layer 2: (8 x 256) @ (256 x 256) -----
    {
        const int wv = t >> 6, l = t & 63;
        const int og = l & 15, rg = l >> 4;
        const int obase = wv * 64 + og;
        const int r0 = rg * 2;
        const float* Wp = W1 + obase;

        float acc2[2][4];
        {
            const float bj0 = b1[obase], bj1 = b1[obase + 16],
                        bj2 = b1[obase + 32], bj3 = b1[obase + 48];
            #pragma unroll
            for (int rr = 0; rr < 2; ++rr) {
                acc2[rr][0] = bj0; acc2[rr][1] = bj1;
                acc2[rr][2] = bj2; acc2[rr][3] = bj3;
            }
        }
        for (int k4 = 0; k4 < 64; ++k4) {
            float4 hv[2];
            #pragma unroll
            for (int rr = 0; rr < 2; ++rr)
                hv[rr] = *reinterpret_cast<const float4*>(&h1[r0 + rr][k4 * 4]);
            #pragma unroll
            for (int kk = 0; kk < 4; ++kk) {
                const float* wrow = Wp + (k4 * 4 + kk) * 256;
                const float wj0 = wrow[0],  wj1 = wrow[16],
                            wj2 = wrow[32], wj3 = wrow[48];
                #pragma unroll
                for (int rr = 0; rr < 2; ++rr) {
                    const float hvv = (kk == 0) ? hv[rr].x : (kk == 1) ? hv[rr].y
                                    : (kk == 2) ? hv[rr].z : hv[rr].w;
                    acc2[rr][0] = fmaf(hvv, wj0, acc2[rr][0]);
                    acc2[rr][1] = fmaf(hvv, wj1, acc2[rr][1]);
                    acc2[rr][2] = fmaf(hvv, wj2, acc2[rr][2]);
                    acc2[rr][3] = fmaf(hvv, wj3, acc2[rr][3]);
                }
            }
        }
        #pragma unroll
        for (int rr = 0; rr < 2; ++rr) {
            #pragma unroll
            for (int j = 0; j < 4; ++j)
                h2[r0 + rr][obase + 16 * j] = fmaxf(acc2[rr][j], 0.0f);
        }
    }
    __syncthreads();

    // ----- layer 3: (8 x 256) @ (256 x 8); threads 0..63 -> (row, z) -----
    if (t < 64) {
        const int r = t >> 3, z = t & 7;
        float a = b2[z];
        #pragma unroll 8
        for (int k4 = 0; k4 < 64; ++k4) {
            const float4 h = *reinterpret_cast<const float4*>(&h2[r][k4 * 4]);
            a = fmaf(h.x, W2[(k4 * 4 + 0) * 8 + z], a);
            a = fmaf(h.y, W2[(k4 * 4 + 1) * 8 + z], a);
            a = fmaf(h.z, W2[(k4 * 4 + 2) * 8 + z], a);
            a = fmaf(h.w, W2[(k4 * 4 + 3) * 8 + z], a);
        }
        const int n  = row0 + r;
        const int b  = n >> 10, nn = n & 1023;
        const int oi = ((b << 3) + z) * 1024 + nn;
        if (msel == 0) wd[oi] = expf(a);
        else           wu[oi] = a;
    }
}

// ---------------------------------------------------------------------------
// Kernel B: persistent zero-fill, PLAIN float4 stores (L2 write-aggregated
// drain — the path fillBuffer/copy use at 6.5+ TB/s). 2048 blocks x 256
// threads x 96 iters; per iteration the whole grid writes one contiguous
// 8 MB slab (wave writes 1 KB contiguous). Runs AFTER the MLP kernel so L2
// pollution cannot hurt W1 reads (round-4/5 lesson).
// ---------------------------------------------------------------------------
__global__ __launch_bounds__(256) void fill_kernel(float4* __restrict__ out4)
{
    unsigned idx = blockIdx.x * 256u + threadIdx.x;    // float4 units
    const float4 z = make_float4(0.f, 0.f, 0.f, 0.f);
    #pragma unroll 8
    for (int it = 0; it < 96; ++it) {
        out4[idx] = z;
        idx += 2048u * 256u;     // 2048*256*96 = 50331648 float4 total
    }
}

// ---------------------------------------------------------------------------
// Kernel C: rewrite only the float4s containing band values.
// One thread per matrix row: g in [0, 3*64*1024).
//   D:    [i][i]   = d[i]
//   Bmat: [i][i]   = d[i],           [i][i+1] = u[i]
//   P:    [i][i-1] = d[i-1]*u[i-1],  [i][i]   = d[i]^2+u[i-1]^2+eps,
//         [i][i+1] = d[i]*u[i]
// ---------------------------------------------------------------------------
__global__ __launch_bounds__(256) void band_kernel(
    const float* __restrict__ wd, const float* __restrict__ wu,
    float4* __restrict__ out4)
{
    const int g    = blockIdx.x * 256 + threadIdx.x;  // 0..196607
    const int tsel = g >> 16;           // 0=D, 1=Bmat, 2=precision
    const int bz   = (g >> 10) & 63;
    const int i    = g & 1023;

    const float* dp = wd + (bz << 10);
    const float* up = wu + (bz << 10);
    const float di = dp[i];
    const float ui = up[i];
    const float dm = (i > 0) ? dp[i - 1] : 0.f;
    const float um = (i > 0) ? up[i - 1] : 0.f;

    int lo, hi;
    if (tsel == 0)      { lo = i >> 2; hi = lo; }
    else if (tsel == 1) { lo = i >> 2; hi = ((i < 1023) ? (i + 1) : i) >> 2; }
    else                { lo = ((i > 0) ? (i - 1) : 0) >> 2;
                          hi = ((i < 1023) ? (i + 1) : i) >> 2; }

    const unsigned rowbase = ((unsigned)g) << 8;   // row start in float4 units

    for (int cb = lo; cb <= hi; ++cb) {
        float vv[4];
        #pragma unroll
        for (int qq = 0; qq < 4; ++qq) {
            const int j = cb * 4 + qq;
            float val = 0.f;
            if (tsel == 0) {
                if (j == i) val = di;
            } else if (tsel == 1) {
                if (j == i)          val = di;
                else if (j == i + 1) val = ui;
            } else {
                if (j == i - 1)      val = dm * um;
                else if (j == i)     val = fmaf(di, di, fmaf(um, um, EPSV));
                else if (j == i + 1) val = di * ui;
            }
            vv[qq] = val;
        }
        out4[rowbase + cb] = make_float4(vv[0], vv[1], vv[2], vv[3]);
    }
}

extern "C" void kernel_launch(void* const* d_in, const int* in_sizes, int n_in,
                              void* d_out, int out_size, void* d_ws, size_t ws_size,
                              hipStream_t stream) {
    const float* x   = (const float*)d_in[0];
    const float* dW0 = (const float*)d_in[1];
    const float* db0 = (const float*)d_in[2];
    const float* dW1 = (const float*)d_in[3];
    const float* db1 = (const float*)d_in[4];
    const float* dW2 = (const float*)d_in[5];
    const float* db2 = (const float*)d_in[6];
    const float* oW0 = (const float*)d_in[7];
    const float* ob0 = (const float*)d_in[8];
    const float* oW1 = (const float*)d_in[9];
    const float* ob1 = (const float*)d_in[10];
    const float* oW2 = (const float*)d_in[11];
    const float* ob2 = (const float*)d_in[12];

    float* wsf = (float*)d_ws;
    float* wd  = wsf;            // 64*1024 floats
    float* wu  = wsf + 65536;    // 64*1024 floats

    mlp_kernel<<<2048, 256, 0, stream>>>(x, dW0, db0, dW1, db1, dW2, db2,
                                         oW0, ob0, oW1, ob1, oW2, ob2, wd, wu);

    fill_kernel<<<2048, 256, 0, stream>>>((float4*)d_out);

    band_kernel<<<768, 256, 0, stream>>>(wd, wu, (float4*)d_out);
}

// Round 10
// 186.381 us; speedup vs baseline: 1.6627x; 1.6627x over previous
//
#include <hip/hip_runtime.h>

#define EPSV 0.001f

typedef float f32x4 __attribute__((ext_vector_type(4)));

// ---------------------------------------------------------------------------
// Fused kernel: 4096 blocks x 256 threads. Slab g (g=0..95) is the float4
// range [g*524288, (g+1)*524288) of the 805 MB output.
//   even bid -> pure fill block: slabs 0..54  at lane offset (bid>>1)*256+t
//   odd  bid -> MLP block (8 rows of one MLP), THEN fills slabs 55..95.
// All stores nontemporal (r4/5/9 A/Bs: nt is the fast path for this stream;
// plain stores measured 2.8-4.2 TB/s vs nt 5.4 TB/s).
// After the ~20 us MLP phase, all 32 waves/CU issue stores (vs 16 in r8).
// Band values are written by band_kernel afterwards (separate dispatch).
// ---------------------------------------------------------------------------
__global__ __launch_bounds__(256) void fused_kernel(
    const float* __restrict__ x,
    const float* __restrict__ dW0, const float* __restrict__ db0,
    const float* __restrict__ dW1, const float* __restrict__ db1,
    const float* __restrict__ dW2, const float* __restrict__ db2,
    const float* __restrict__ oW0, const float* __restrict__ ob0,
    const float* __restrict__ oW1, const float* __restrict__ ob1,
    const float* __restrict__ oW2, const float* __restrict__ ob2,
    float* __restrict__ wd, float* __restrict__ wu,
    float4* __restrict__ out4)
{
    __shared__ float xs[8][32];
    __shared__ float h1[8][260];
    __shared__ float h2[8][260];

    const int bid = blockIdx.x;
    const int t   = threadIdx.x;
    const f32x4 z = {0.f, 0.f, 0.f, 0.f};

    if ((bid & 1) == 0) {
        // ---------- pure fill role (2048 blocks): slabs 0..54 ----------
        const unsigned pf = (unsigned)(bid >> 1);             // 0..2047
        unsigned idx = pf * 256u + (unsigned)t;               // float4 units
        #pragma unroll 5
        for (int g = 0; g < 55; ++g) {
            __builtin_nontemporal_store(z, (f32x4*)&out4[idx]);
            idx += 524288u;        // next slab (8 MB / 16 B)
        }
        return;
    }

    // ---------------- MLP role (2048 blocks) ----------------
    const int mlpid = bid >> 1;           // 0..2047
    const int msel  = mlpid & 1;          // 0 = diag MLP, 1 = offdiag MLP
    const int row0  = (mlpid >> 1) << 3;  // 8 rows of flattened (8192, 32) x

    const float* W0 = msel ? oW0 : dW0;  const float* b0 = msel ? ob0 : db0;
    const float* W1 = msel ? oW1 : dW1;  const float* b1 = msel ? ob1 : db1;
    const float* W2 = msel ? oW2 : dW2;  const float* b2 = msel ? ob2 : db2;

    ((float*)xs)[t] = x[row0 * 32 + t];
    __syncthreads();

    // ----- layer 1: (8 x 32) @ (32 x 256); thread t owns hidden unit t -----
    {
        float acc1[8];
        const float bb = b0[t];
        #pragma unroll
        for (int r = 0; r < 8; ++r) acc1[r] = bb;
        #pragma unroll
        for (int k4 = 0; k4 < 8; ++k4) {
            const float w0 = W0[(k4 * 4 + 0) * 256 + t];
            const float w1 = W0[(k4 * 4 + 1) * 256 + t];
            const float w2 = W0[(k4 * 4 + 2) * 256 + t];
            const float w3 = W0[(k4 * 4 + 3) * 256 + t];
            #pragma unroll
            for (int r = 0; r < 8; ++r) {
                const float4 h = *reinterpret_cast<const float4*>(&xs[r][k4 * 4]);
                acc1[r] = fmaf(h.w, w3, fmaf(h.z, w2, fmaf(h.y, w1, fmaf(h.x, w0, acc1[r]))));
            }
        }
        #pragma unroll
        for (int r = 0; r < 8; ++r) h1[r][t] = fmaxf(acc1[r], 0.0f);
    }
    __syncthreads();

    // ----- layer 2: (8 x 256) @ (256 x 256) -----
    {
        const int wv = t >> 6, l = t & 63;
        const int og = l & 15, rg = l >> 4;
        const int obase = wv * 64 + og;
        const int r0 = rg * 2;
        const float* Wp = W1 + obase;

        float acc2[2][4];
        {
            const float bj0 = b1[obase], bj1 = b1[obase + 16],
                        bj2 = b1[obase + 32], bj3 = b1[obase + 48];
            #pragma unroll
            for (int rr = 0; rr < 2; ++rr) {
                acc2[rr][0] = bj0; acc2[rr][1] = bj1;
                acc2[rr][2] = bj2; acc2[rr][3] = bj3;
            }
        }
        for (int k4 = 0; k4 < 64; ++k4) {
            float4 hv[2];
            #pragma unroll
            for (int rr = 0; rr < 2; ++rr)
                hv[rr] = *reinterpret_cast<const float4*>(&h1[r0 + rr][k4 * 4]);
            #pragma unroll
            for (int kk = 0; kk < 4; ++kk) {
                const float* wrow = Wp + (k4 * 4 + kk) * 256;
                const float wj0 = wrow[0],  wj1 = wrow[16],
                            wj2 = wrow[32], wj3 = wrow[48];
                #pragma unroll
                for (int rr = 0; rr < 2; ++rr) {
                    const float hvv = (kk == 0) ? hv[rr].x : (kk == 1) ? hv[rr].y
                                    : (kk == 2) ? hv[rr].z : hv[rr].w;
                    acc2[rr][0] = fmaf(hvv, wj0, acc2[rr][0]);
                    acc2[rr][1] = fmaf(hvv, wj1, acc2[rr][1]);
                    acc2[rr][2] = fmaf(hvv, wj2, acc2[rr][2]);
                    acc2[rr][3] = fmaf(hvv, wj3, acc2[rr][3]);
                }
            }
        }
        #pragma unroll
        for (int rr = 0; rr < 2; ++rr) {
            #pragma unroll
            for (int j = 0; j < 4; ++j)
                h2[r0 + rr][obase + 16 * j] = fmaxf(acc2[rr][j], 0.0f);
        }
    }
    __syncthreads();

    // ----- layer 3: (8 x 256) @ (256 x 8); threads 0..63 -> (row, z) -----
    if (t < 64) {
        const int r = t >> 3, z = t & 7;
        float a = b2[z];
        #pragma unroll 8
        for (int k4 = 0; k4 < 64; ++k4) {
            const float4 h = *reinterpret_cast<const float4*>(&h2[r][k4 * 4]);
            a = fmaf(h.x, W2[(k4 * 4 + 0) * 8 + z], a);
            a = fmaf(h.y, W2[(k4 * 4 + 1) * 8 + z], a);
            a = fmaf(h.z, W2[(k4 * 4 + 2) * 8 + z], a);
            a = fmaf(h.w, W2[(k4 * 4 + 3) * 8 + z], a);
        }
        const int n  = row0 + r;
        const int b  = n >> 10, nn = n & 1023;
        const int oi = ((b << 3) + z) * 1024 + nn;
        if (msel == 0) wd[oi] = expf(a);
        else           wu[oi] = a;
    }

    // ---------- MLP blocks join the fill: slabs 55..95 ----------
    {
        const unsigned m = (unsigned)(bid >> 1);              // 0..2047
        unsigned idx = 55u * 524288u + m * 256u + (unsigned)t;
        #pragma unroll 5
        for (int g = 0; g < 41; ++g) {
            __builtin_nontemporal_store(z, (f32x4*)&out4[idx]);
            idx += 524288u;
        }
    }
}

// ---------------------------------------------------------------------------
// Band kernel: rewrite only the float4s containing band values.
// One thread per matrix row: g in [0, 3*64*1024).
//   D:    [i][i]   = d[i]
//   Bmat: [i][i]   = d[i],           [i][i+1] = u[i]
//   P:    [i][i-1] = d[i-1]*u[i-1],  [i][i]   = d[i]^2+u[i-1]^2+eps,
//         [i][i+1] = d[i]*u[i]
// ---------------------------------------------------------------------------
__global__ __launch_bounds__(256) void band_kernel(
    const float* __restrict__ wd, const float* __restrict__ wu,
    float4* __restrict__ out4)
{
    const int g    = blockIdx.x * 256 + threadIdx.x;  // 0..196607
    const int tsel = g >> 16;           // 0=D, 1=Bmat, 2=precision
    const int bz   = (g >> 10) & 63;
    const int i    = g & 1023;

    const float* dp = wd + (bz << 10);
    const float* up = wu + (bz << 10);
    const float di = dp[i];
    const float ui = up[i];
    const float dm = (i > 0) ? dp[i - 1] : 0.f;
    const float um = (i > 0) ? up[i - 1] : 0.f;

    int lo, hi;
    if (tsel == 0)      { lo = i >> 2; hi = lo; }
    else if (tsel == 1) { lo = i >> 2; hi = ((i < 1023) ? (i + 1) : i) >> 2; }
    else                { lo = ((i > 0) ? (i - 1) : 0) >> 2;
                          hi = ((i < 1023) ? (i + 1) : i) >> 2; }

    const unsigned rowbase = ((unsigned)g) << 8;   // row start in float4 units

    for (int cb = lo; cb <= hi; ++cb) {
        float vv[4];
        #pragma unroll
        for (int qq = 0; qq < 4; ++qq) {
            const int j = cb * 4 + qq;
            float val = 0.f;
            if (tsel == 0) {
                if (j == i) val = di;
            } else if (tsel == 1) {
                if (j == i)          val = di;
                else if (j == i + 1) val = ui;
            } else {
                if (j == i - 1)      val = dm * um;
                else if (j == i)     val = fmaf(di, di, fmaf(um, um, EPSV));
                else if (j == i + 1) val = di * ui;
            }
            vv[qq] = val;
        }
        out4[rowbase + cb] = make_float4(vv[0], vv[1], vv[2], vv[3]);
    }
}

extern "C" void kernel_launch(void* const* d_in, const int* in_sizes, int n_in,
                              void* d_out, int out_size, void* d_ws, size_t ws_size,
                              hipStream_t stream) {
    const float* x   = (const float*)d_in[0];
    const float* dW0 = (const float*)d_in[1];
    const float* db0 = (const float*)d_in[2];
    const float* dW1 = (const float*)d_in[3];
    const float* db1 = (const float*)d_in[4];
    const float* dW2 = (const float*)d_in[5];
    const float* db2 = (const float*)d_in[6];
    const float* oW0 = (const float*)d_in[7];
    const float* ob0 = (const float*)d_in[8];
    const float* oW1 = (const float*)d_in[9];
    const float* ob1 = (const float*)d_in[10];
    const float* oW2 = (const float*)d_in[11];
    const float* ob2 = (const float*)d_in[12];

    float* wsf = (float*)d_ws;
    float* wd  = wsf;            // 64*1024 floats
    float* wu  = wsf + 65536;    // 64*1024 floats

    fused_kernel<<<4096, 256, 0, stream>>>(x, dW0, db0, dW1, db1, dW2, db2,
                                           oW0, ob0, oW1, ob1, oW2, ob2,
                                           wd, wu, (float4*)d_out);

    band_kernel<<<768, 256, 0, stream>>>(wd, wu, (float4*)d_out);
}

// Round 11
// 174.874 us; speedup vs baseline: 1.7721x; 1.0658x over previous
//
#include <hip/hip_runtime.h>

#define EPSV 0.001f

typedef float f32x4 __attribute__((ext_vector_type(4)));

// ---------------------------------------------------------------------------
// Fused kernel: 4096 blocks x 256 threads.  (round-8 optimum, restored)
//   even bid -> persistent zero-fill block (2048 blocks; 96 nt float4 stores
//               each, grid-stride; whole grid writes one contiguous 8 MB slab
//               per iteration). No launch churn: 4 fill blocks/CU resident
//               for the whole kernel.
//   odd bid  -> MLP block (2048 blocks; 8 rows of one MLP each).
// nt stores: measured fastest path for this 805 MB stream (5.4 TB/s vs
// 2.8-4.5 TB/s for plain at every shape tried; vendor fill = 1.6 TB/s at
// this size). Adding more store waves (r10) or serializing (r6/r9) is worse.
// Band values are written by band_kernel afterwards (separate dispatch).
// ---------------------------------------------------------------------------
__global__ __launch_bounds__(256) void fused_kernel(
    const float* __restrict__ x,
    const float* __restrict__ dW0, const float* __restrict__ db0,
    const float* __restrict__ dW1, const float* __restrict__ db1,
    const float* __restrict__ dW2, const float* __restrict__ db2,
    const float* __restrict__ oW0, const float* __restrict__ ob0,
    const float* __restrict__ oW1, const float* __restrict__ ob1,
    const float* __restrict__ oW2, const float* __restrict__ ob2,
    float* __restrict__ wd, float* __restrict__ wu,
    float4* __restrict__ out4)
{
    __shared__ float xs[8][32];
    __shared__ float h1[8][260];
    __shared__ float h2[8][260];

    const int bid = blockIdx.x;
    const int t   = threadIdx.x;

    if ((bid & 1) == 0) {
        // ---------- persistent zero-fill role (2048 blocks) ----------
        const unsigned fid = (unsigned)(bid >> 1);            // 0..2047
        unsigned idx = fid * 256u + (unsigned)t;              // float4 units
        const f32x4 z = {0.f, 0.f, 0.f, 0.f};
        #pragma unroll 8
        for (int it = 0; it < 96; ++it) {
            __builtin_nontemporal_store(z, (f32x4*)&out4[idx]);
            idx += 2048u * 256u;     // 2048*256*96 = 50331648 float4 total
        }
        return;
    }

    // ---------------- MLP role (2048 blocks) ----------------
    const int mlpid = bid >> 1;           // 0..2047
    const int msel  = mlpid & 1;          // 0 = diag MLP, 1 = offdiag MLP
    const int row0  = (mlpid >> 1) << 3;  // 8 rows of flattened (8192, 32) x

    const float* W0 = msel ? oW0 : dW0;  const float* b0 = msel ? ob0 : db0;
    const float* W1 = msel ? oW1 : dW1;  const float* b1 = msel ? ob1 : db1;
    const float* W2 = msel ? oW2 : dW2;  const float* b2 = msel ? ob2 : db2;

    ((float*)xs)[t] = x[row0 * 32 + t];
    __syncthreads();

    // ----- layer 1: (8 x 32) @ (32 x 256); thread t owns hidden unit t -----
    {
        float acc1[8];
        const float bb = b0[t];
        #pragma unroll
        for (int r = 0; r < 8; ++r) acc1[r] = bb;
        #pragma unroll
        for (int k4 = 0; k4 < 8; ++k4) {
            const float w0 = W0[(k4 * 4 + 0) * 256 + t];
            const float w1 = W0[(k4 * 4 + 1) * 256 + t];
            const float w2 = W0[(k4 * 4 + 2) * 256 + t];
            const float w3 = W0[(k4 * 4 + 3) * 256 + t];
            #pragma unroll
            for (int r = 0; r < 8; ++r) {
                const float4 h = *reinterpret_cast<const float4*>(&xs[r][k4 * 4]);
                acc1[r] = fmaf(h.w, w3, fmaf(h.z, w2, fmaf(h.y, w1, fmaf(h.x, w0, acc1[r]))));
            }
        }
        #pragma unroll
        for (int r = 0; r < 8; ++r) h1[r][t] = fmaxf(acc1[r], 0.0f);
    }
    __syncthreads();

    // ----- layer 2: (8 x 256) @ (256 x 256) -----
    {
        const int wv = t >> 6, l = t & 63;
        const int og = l & 15, rg = l >> 4;
        const int obase = wv * 64 + og;
        const int r0 = rg * 2;
        const float* Wp = W1 + obase;

        float acc2[2][4];
        {
            const float bj0 = b1[obase], bj1 = b1[obase + 16],
                        bj2 = b1[obase + 32], bj3 = b1[obase + 48];
            #pragma unroll
            for (int rr = 0; rr < 2; ++rr) {
                acc2[rr][0] = bj0; acc2[rr][1] = bj1;
                acc2[rr][2] = bj2; acc2[rr][3] = bj3;
            }
        }
        for (int k4 = 0; k4 < 64; ++k4) {
            float4 hv[2];
            #pragma unroll
            for (int rr = 0; rr < 2; ++rr)
                hv[rr] = *reinterpret_cast<const float4*>(&h1[r0 + rr][k4 * 4]);
            #pragma unroll
            for (int kk = 0; kk < 4; ++kk) {
                const float* wrow = Wp + (k4 * 4 + kk) * 256;
                const float wj0 = wrow[0],  wj1 = wrow[16],
                            wj2 = wrow[32], wj3 = wrow[48];
                #pragma unroll
                for (int rr = 0; rr < 2; ++rr) {
                    const float hvv = (kk == 0) ? hv[rr].x : (kk == 1) ? hv[rr].y
                                    : (kk == 2) ? hv[rr].z : hv[rr].w;
                    acc2[rr][0] = fmaf(hvv, wj0, acc2[rr][0]);
                    acc2[rr][1] = fmaf(hvv, wj1, acc2[rr][1]);
                    acc2[rr][2] = fmaf(hvv, wj2, acc2[rr][2]);
                    acc2[rr][3] = fmaf(hvv, wj3, acc2[rr][3]);
                }
            }
        }
        #pragma unroll
        for (int rr = 0; rr < 2; ++rr) {
            #pragma unroll
            for (int j = 0; j < 4; ++j)
                h2[r0 + rr][obase + 16 * j] = fmaxf(acc2[rr][j], 0.0f);
        }
    }
    __syncthreads();

    // ----- layer 3: (8 x 256) @ (256 x 8); threads 0..63 -> (row, z) -----
    if (t < 64) {
        const int r = t >> 3, z = t & 7;
        float a = b2[z];
        #pragma unroll 8
        for (int k4 = 0; k4 < 64; ++k4) {
            const float4 h = *reinterpret_cast<const float4*>(&h2[r][k4 * 4]);
            a = fmaf(h.x, W2[(k4 * 4 + 0) * 8 + z], a);
            a = fmaf(h.y, W2[(k4 * 4 + 1) * 8 + z], a);
            a = fmaf(h.z, W2[(k4 * 4 + 2) * 8 + z], a);
            a = fmaf(h.w, W2[(k4 * 4 + 3) * 8 + z], a);
        }
        const int n  = row0 + r;
        const int b  = n >> 10, nn = n & 1023;
        const int oi = ((b << 3) + z) * 1024 + nn;
        if (msel == 0) wd[oi] = expf(a);
        else           wu[oi] = a;
    }
}

// ---------------------------------------------------------------------------
// Band kernel: rewrite only the float4s containing band values.
// One thread per matrix row: g in [0, 3*64*1024).
//   D:    [i][i]   = d[i]
//   Bmat: [i][i]   = d[i],           [i][i+1] = u[i]
//   P:    [i][i-1] = d[i-1]*u[i-1],  [i][i]   = d[i]^2+u[i-1]^2+eps,
//         [i][i+1] = d[i]*u[i]
// ---------------------------------------------------------------------------
__global__ __launch_bounds__(256) void band_kernel(
    const float* __restrict__ wd, const float* __restrict__ wu,
    float4* __restrict__ out4)
{
    const int g    = blockIdx.x * 256 + threadIdx.x;  // 0..196607
    const int tsel = g >> 16;           // 0=D, 1=Bmat, 2=precision
    const int bz   = (g >> 10) & 63;
    const int i    = g & 1023;

    const float* dp = wd + (bz << 10);
    const float* up = wu + (bz << 10);
    const float di = dp[i];
    const float ui = up[i];
    const float dm = (i > 0) ? dp[i - 1] : 0.f;
    const float um = (i > 0) ? up[i - 1] : 0.f;

    int lo, hi;
    if (tsel == 0)      { lo = i >> 2; hi = lo; }
    else if (tsel == 1) { lo = i >> 2; hi = ((i < 1023) ? (i + 1) : i) >> 2; }
    else                { lo = ((i > 0) ? (i - 1) : 0) >> 2;
                          hi = ((i < 1023) ? (i + 1) : i) >> 2; }

    const unsigned rowbase = ((unsigned)g) << 8;   // row start in float4 units

    for (int cb = lo; cb <= hi; ++cb) {
        float vv[4];
        #pragma unroll
        for (int qq = 0; qq < 4; ++qq) {
            const int j = cb * 4 + qq;
            float val = 0.f;
            if (tsel == 0) {
                if (j == i) val = di;
            } else if (tsel == 1) {
                if (j == i)          val = di;
                else if (j == i + 1) val = ui;
            } else {
                if (j == i - 1)      val = dm * um;
                else if (j == i)     val = fmaf(di, di, fmaf(um, um, EPSV));
                else if (j == i + 1) val = di * ui;
            }
            vv[qq] = val;
        }
        out4[rowbase + cb] = make_float4(vv[0], vv[1], vv[2], vv[3]);
    }
}

extern "C" void kernel_launch(void* const* d_in, const int* in_sizes, int n_in,
                              void* d_out, int out_size, void* d_ws, size_t ws_size,
                              hipStream_t stream) {
    const float* x   = (const float*)d_in[0];
    const float* dW0 = (const float*)d_in[1];
    const float* db0 = (const float*)d_in[2];
    const float* dW1 = (const float*)d_in[3];
    const float* db1 = (const float*)d_in[4];
    const float* dW2 = (const float*)d_in[5];
    const float* db2 = (const float*)d_in[6];
    const float* oW0 = (const float*)d_in[7];
    const float* ob0 = (const float*)d_in[8];
    const float* oW1 = (const float*)d_in[9];
    const float* ob1 = (const float*)d_in[10];
    const float* oW2 = (const float*)d_in[11];
    const float* ob2 = (const float*)d_in[12];

    float* wsf = (float*)d_ws;
    float* wd  = wsf;            // 64*1024 floats
    float* wu  = wsf + 65536;    // 64*1024 floats

    fused_kernel<<<4096, 256, 0, stream>>>(x, dW0, db0, dW1, db1, dW2, db2,
                                           oW0, ob0, oW1, ob1, oW2, ob2,
                                           wd, wu, (float4*)d_out);

    band_kernel<<<768, 256, 0, stream>>>(wd, wu, (float4*)d_out);
}